// Round 12
// baseline (70.335 us; speedup 1.0000x reference)
//
#include <hip/hip_runtime.h>
#include <hip/hip_fp16.h>

#define B_  64
#define L_  512
#define D_  768
#define S_  64
#define M_  4096
#define N1_ 384
#define N2_ 128
#define SEG_C 4               // segments per mean block
#define NMB (M_ / SEG_C)      // 1024 mean blocks

#define NG1 384               // gemm1 tiles (6 per sample)
#define NG2 64                // gemm2 blocks (1 per sample)

typedef __attribute__((ext_vector_type(8))) _Float16 half8;
typedef __attribute__((ext_vector_type(4))) float f32x4;

__device__ __forceinline__ ushort f2h(float x) {
  return __half_as_ushort(__float2half_rn(x));
}

// ---------------------------------------------------------------------------
// Kernel 1: blocks 0..1023 streaming segment-mean (R9, measured ~18us = BW
// floor); blocks 1024.. weight transpose to f16 B^T. Weight-block 0 also
// zeroes the q counters for the fused gemm kernel (same-stream ordering
// guarantees visibility before launch 2 starts).
// ---------------------------------------------------------------------------
__global__ __launch_bounds__(192) void mean_prep_kernel(
    const float* __restrict__ hidden, const int* __restrict__ seg_ids,
    ushort* __restrict__ mh,
    const float* __restrict__ W1, ushort* __restrict__ w1t,
    const float* __restrict__ W2, ushort* __restrict__ w2t,
    unsigned int* __restrict__ q) {
  const int bid = blockIdx.x;
  const int tid = threadIdx.x;

  if (bid < NMB) {
    const int b  = bid >> 4;
    const int s0 = (bid & 15) * SEG_C;
    __shared__ int sids[L_];
    __shared__ int wred[3];
    int pk = 0;
    if (tid < 128) {
      int4 v = ((const int4*)(seg_ids + b * L_))[tid];
      ((int4*)sids)[tid] = v;
      int clo = (v.x < s0) + (v.y < s0) + (v.z < s0) + (v.w < s0);
      int chi = (v.x < s0 + SEG_C) + (v.y < s0 + SEG_C) +
                (v.z < s0 + SEG_C) + (v.w < s0 + SEG_C);
      pk = clo * 1024 + chi;   // both <= 512: no carry between fields
    }
    #pragma unroll
    for (int off = 1; off < 64; off <<= 1) pk += __shfl_xor(pk, off);
    if ((tid & 63) == 0) wred[tid >> 6] = pk;
    __syncthreads();
    const int tot = wred[0] + wred[1] + wred[2];
    const int lo = tot >> 10;
    const int hi = tot & 1023;

    const float4* hp = (const float4*)(hidden + (size_t)b * L_ * D_) + tid;
    ushort* outb = mh + (size_t)b * S_ * D_ + tid * 4;  // row stride D_
    const uint2 zz = {0u, 0u};

    int cur = (lo < hi) ? sids[lo] : s0 + SEG_C;
    for (int z = s0; z < cur; ++z)
      *(uint2*)(outb + (size_t)z * D_) = zz;

    float4 acc = {0.0f, 0.0f, 0.0f, 0.0f};
    int segstart = lo;
    for (int l = lo; l < hi; l += 8) {
      float4 v[8];
      int sv[8];
      #pragma unroll
      for (int k = 0; k < 8; ++k) {
        v[k]  = hp[(size_t)min(l + k, hi - 1) * (D_ / 4)];
        sv[k] = sids[min(l + k + 1, hi - 1)];
      }
      #pragma unroll
      for (int k = 0; k < 8; ++k) {
        if (l + k < hi) {
          acc.x += v[k].x; acc.y += v[k].y;
          acc.z += v[k].z; acc.w += v[k].w;
          const int nx = l + k + 1;
          if (nx == hi || sv[k] != cur) {
            const float inv = 1.0f / (float)(nx - segstart);
            ushort4 h;
            h.x = f2h(acc.x * inv); h.y = f2h(acc.y * inv);
            h.z = f2h(acc.z * inv); h.w = f2h(acc.w * inv);
            *(ushort4*)(outb + (size_t)cur * D_) = h;
            const int nxt = (nx == hi) ? s0 + SEG_C : sv[k];
            for (int z = cur + 1; z < nxt; ++z)
              *(uint2*)(outb + (size_t)z * D_) = zz;
            acc.x = 0.0f; acc.y = 0.0f; acc.z = 0.0f; acc.w = 0.0f;
            segstart = nx; cur = nxt;
          }
        }
      }
    }
  } else {
    // ---- weight transpose, single f16 (32x32 tiles, 192 threads) ----
    int wb = bid - NMB;
    if (wb == 0 && tid < 64) q[tid] = 0u;   // zero per-sample counters
    const float* W; ushort* Wt; int K, N, nblk, kblk;
    if (wb < 288) {  // W1: 12 col-tiles x 24 row-tiles
      W = W1; Wt = w1t; K = D_; N = N1_;
      nblk = wb % 12; kblk = wb / 12;
    } else {         // W2: 4 x 12
      wb -= 288;
      W = W2; Wt = w2t; K = N1_; N = N2_;
      nblk = wb % 4; kblk = wb / 4;
    }
    __shared__ float tile[32][33];
    const int n0 = nblk * 32, k0 = kblk * 32;
    const int tx = tid & 31, ty = tid >> 5;  // 32 x 6
    for (int r = ty; r < 32; r += 6)
      tile[r][tx] = W[(size_t)(k0 + r) * N + n0 + tx];
    __syncthreads();
    for (int r = ty; r < 32; r += 6)
      Wt[(size_t)(n0 + r) * K + k0 + tx] = f2h(tile[tx][r]);
  }
}

// ---------------------------------------------------------------------------
// Kernel 2 (fused): blocks 0..383 = gemm1 64x64 tiles (f16 MFMA, 8-wave
// K-split, DOUBLE-buffered LDS -> 1 barrier per k-tile), signal q[sample]
// on completion. Blocks 384..447 = per-sample gemm2+final, acquire-spin on
// q[sample]==6. Co-residency: 448 blocks, >=4 blocks/CU capacity (1024) ->
// deadlock-free regardless of dispatch order.
// ---------------------------------------------------------------------------
__global__ __launch_bounds__(512) void fused_gemm(
    const ushort* __restrict__ As, const ushort* __restrict__ w1t,
    const float* __restrict__ b1, ushort* __restrict__ h1,
    const ushort* __restrict__ w2t, const float* __restrict__ b2,
    const float* __restrict__ W3, const float* __restrict__ b3,
    float* __restrict__ out, unsigned int* __restrict__ q) {
  __shared__ __align__(16) char lds[36864 + 512];
  const int bid = blockIdx.x;
  const int tid = threadIdx.x;
  const int wid = tid >> 6, lane = tid & 63;
  const int lrow = lane & 15, lk = (lane >> 4) * 8;

  if (bid < NG1) {
    // ================= gemm1 tile =================
    constexpr int LDK = 72;
    constexpr int SEG = 64 * LDK;       // one operand (A or B), ushorts
    constexpr int BUFSZ = 2 * SEG;      // one buffer (A+B)
    ushort* smem = (ushort*)lds;
    const int b = bid / 6, nt = bid % 6;
    const int w2v = wid & 3;
    const int kh = (wid >> 2) * 32;
    const int m0 = (w2v >> 1) * 32;
    const int n0g = (w2v & 1) * 32;
    const int hf = tid >> 8, t8 = tid & 255;
    const int srow = t8 >> 2, sk = (t8 & 3) * 16;
    const int soff = hf * SEG + srow * LDK + sk;
    const int brow = b * 64, bcol = nt * 64;
    const ushort* gp = hf ? (w1t + (size_t)(bcol + srow) * D_ + sk)
                          : (As + (size_t)(brow + srow) * D_ + sk);

    uint4 r0 = *(const uint4*)gp;
    uint4 r1 = *(const uint4*)(gp + 8);
    *(uint4*)&smem[soff]     = r0;
    *(uint4*)&smem[soff + 8] = r1;
    __syncthreads();

    f32x4 acc[2][2] = {};
    #pragma unroll 1
    for (int t = 0; t < 12; ++t) {
      const int curoff = (t & 1) * BUFSZ;
      if (t + 1 < 12) {
        r0 = *(const uint4*)(gp + (size_t)(t + 1) * 64);
        r1 = *(const uint4*)(gp + (size_t)(t + 1) * 64 + 8);
      }
      half8 av[2], bv[2];
      #pragma unroll
      for (int i = 0; i < 2; ++i) {
        av[i] = *(const half8*)&smem[curoff + (m0 + i * 16 + lrow) * LDK + kh + lk];
        bv[i] = *(const half8*)&smem[curoff + SEG + (n0g + i * 16 + lrow) * LDK + kh + lk];
      }
      #pragma unroll
      for (int i = 0; i < 2; ++i)
        #pragma unroll
        for (int j = 0; j < 2; ++j)
          acc[i][j] = __builtin_amdgcn_mfma_f32_16x16x32_f16(av[i], bv[j], acc[i][j], 0, 0, 0);
      if (t + 1 < 12) {
        const int nxt = ((t & 1) ^ 1) * BUFSZ;
        *(uint4*)&smem[nxt + soff]     = r0;
        *(uint4*)&smem[nxt + soff + 8] = r1;
        __syncthreads();
      }
    }
    __syncthreads();   // drain last reads before smem reuse as f32 scratch

    // combine K-split halves through LDS (stride 18 dwords: 2-way alias)
    float* red = (float*)lds;
    const int roff = (w2v * 64 + lane) * 18;
    if (wid >= 4) {
      #pragma unroll
      for (int i = 0; i < 2; ++i)
        #pragma unroll
        for (int j = 0; j < 2; ++j) {
          *(float2*)&red[roff + i * 8 + j * 4]     = make_float2(acc[i][j][0], acc[i][j][1]);
          *(float2*)&red[roff + i * 8 + j * 4 + 2] = make_float2(acc[i][j][2], acc[i][j][3]);
        }
    }
    __syncthreads();
    if (wid < 4) {
      #pragma unroll
      for (int i = 0; i < 2; ++i)
        #pragma unroll
        for (int j = 0; j < 2; ++j) {
          float2 p0 = *(float2*)&red[roff + i * 8 + j * 4];
          float2 p1 = *(float2*)&red[roff + i * 8 + j * 4 + 2];
          acc[i][j][0] += p0.x; acc[i][j][1] += p0.y;
          acc[i][j][2] += p1.x; acc[i][j][3] += p1.y;
          const float bj = b1[bcol + n0g + j * 16 + lrow];
          #pragma unroll
          for (int r = 0; r < 4; ++r) {
            float v = fmaxf(acc[i][j][r] + bj, 0.0f);
            h1[(size_t)(brow + m0 + i * 16 + (lane >> 4) * 4 + r) * N1_ +
               bcol + n0g + j * 16 + lrow] = f2h(v);
          }
        }
    }
    __syncthreads();
    if (tid == 0) {
      __threadfence();
      __hip_atomic_fetch_add(&q[b], 1u, __ATOMIC_RELEASE, __HIP_MEMORY_SCOPE_AGENT);
    }

  } else {
    // ================= gemm2 + final for one sample (64 rows) =================
    const int b = bid - NG1;
    if (tid == 0) {
      while (__hip_atomic_load(&q[b], __ATOMIC_ACQUIRE, __HIP_MEMORY_SCOPE_AGENT) < 6u)
        __builtin_amdgcn_s_sleep(8);
      __threadfence();
    }
    __syncthreads();

    constexpr int LDA2 = 40;
    ushort* sA2 = (ushort*)lds;                  // [2][64*40]   = 10240 B
    ushort* sB2 = (ushort*)(lds + 10240);        // [2][128*40]  = 20480 B
    float*  pl  = (float*)(lds + 30720);         // 128 floats
    const int hw = wid >> 2;                     // row half: 0 or 1
    const int n0 = (wid & 3) * 32;
    const int rbase = hw * 32;
    const int brow = b * 64;

    const ushort* pA = nullptr; const ushort* pB = nullptr;
    int offA = 0, offB = 0;
    if (tid < 256) {
      const int srA = tid >> 2, skA = (tid & 3) * 8;
      pA = h1 + (size_t)(brow + srA) * N1_ + skA;
      offA = srA * LDA2 + skA;
    } else {
      const int t8 = tid - 256;
      const int srB = t8 >> 1, skB = (t8 & 1) * 16;
      pB = w2t + (size_t)srB * N1_ + skB;
      offB = srB * LDA2 + skB;
    }
    uint4 ra = {0,0,0,0}, rb0 = {0,0,0,0}, rb1 = {0,0,0,0};
    if (tid < 256) ra = *(const uint4*)pA;
    else { rb0 = *(const uint4*)pB; rb1 = *(const uint4*)(pB + 8); }
    if (tid < 256) *(uint4*)&sA2[offA] = ra;
    else { *(uint4*)&sB2[offB] = rb0; *(uint4*)&sB2[offB + 8] = rb1; }
    __syncthreads();

    f32x4 acc[2][2] = {};
    #pragma unroll 1
    for (int kt = 0; kt < 12; ++kt) {
      const int cur = kt & 1;
      if (kt + 1 < 12) {
        if (tid < 256) ra = *(const uint4*)(pA + (size_t)(kt + 1) * 32);
        else {
          rb0 = *(const uint4*)(pB + (size_t)(kt + 1) * 32);
          rb1 = *(const uint4*)(pB + (size_t)(kt + 1) * 32 + 8);
        }
      }
      half8 av[2], bv[2];
      #pragma unroll
      for (int i = 0; i < 2; ++i)
        av[i] = *(const half8*)&sA2[cur * 2560 + (rbase + i * 16 + lrow) * LDA2 + lk];
      #pragma unroll
      for (int j = 0; j < 2; ++j)
        bv[j] = *(const half8*)&sB2[cur * 5120 + (n0 + j * 16 + lrow) * LDA2 + lk];
      #pragma unroll
      for (int i = 0; i < 2; ++i)
        #pragma unroll
        for (int j = 0; j < 2; ++j)
          acc[i][j] = __builtin_amdgcn_mfma_f32_16x16x32_f16(av[i], bv[j], acc[i][j], 0, 0, 0);
      if (kt + 1 < 12) {
        __syncthreads();
        const int nxt = cur ^ 1;
        if (tid < 256) *(uint4*)&sA2[nxt * 2560 + offA] = ra;
        else { *(uint4*)&sB2[nxt * 5120 + offB] = rb0; *(uint4*)&sB2[nxt * 5120 + offB + 8] = rb1; }
        __syncthreads();
      }
    }

    __syncthreads();
    if (tid < 128) pl[tid] = 0.0f;
    float w3v[2][2], b2v[2];
    #pragma unroll
    for (int j = 0; j < 2; ++j) {
      const int col = n0 + j * 16 + lrow;
      w3v[j][0] = W3[col * 2 + 0];
      w3v[j][1] = W3[col * 2 + 1];
      b2v[j] = b2[col];
    }
    __syncthreads();
    #pragma unroll
    for (int i = 0; i < 2; ++i)
      #pragma unroll
      for (int r = 0; r < 4; ++r) {
        float p0 = 0.0f, p1 = 0.0f;
        #pragma unroll
        for (int j = 0; j < 2; ++j) {
          float v = fmaxf(acc[i][j][r] + b2v[j], 0.0f);
          p0 += v * w3v[j][0];
          p1 += v * w3v[j][1];
        }
        p0 += __shfl_xor(p0, 1); p1 += __shfl_xor(p1, 1);
        p0 += __shfl_xor(p0, 2); p1 += __shfl_xor(p1, 2);
        p0 += __shfl_xor(p0, 4); p1 += __shfl_xor(p1, 4);
        p0 += __shfl_xor(p0, 8); p1 += __shfl_xor(p1, 8);
        if (lrow == 0) {
          const int row = rbase + i * 16 + (lane >> 4) * 4 + r;   // 0..63
          atomicAdd(&pl[row * 2 + 0], p0);
          atomicAdd(&pl[row * 2 + 1], p1);
        }
      }
    __syncthreads();
    if (tid < 128) {
      const int row = tid >> 1, c = tid & 1;
      out[(size_t)(brow + row) * 2 + c] = pl[tid] + b3[c];
    }
  }
}

// ---------------------------------------------------------------------------
extern "C" void kernel_launch(void* const* d_in, const int* in_sizes, int n_in,
                              void* d_out, int out_size, void* d_ws, size_t ws_size,
                              hipStream_t stream) {
  const float* hidden  = (const float*)d_in[0];
  const int*   seg_ids = (const int*)d_in[1];
  const float* W1 = (const float*)d_in[2];
  const float* b1 = (const float*)d_in[3];
  const float* W2 = (const float*)d_in[4];
  const float* b2 = (const float*)d_in[5];
  const float* W3 = (const float*)d_in[6];
  const float* b3 = (const float*)d_in[7];
  float* out = (float*)d_out;

  char* p = (char*)d_ws;
  ushort* mh  = (ushort*)p;  p += (size_t)M_ * D_ * 2;     // means f16
  ushort* w1t = (ushort*)p;  p += (size_t)N1_ * D_ * 2;    // W1^T f16
  ushort* h1  = (ushort*)p;  p += (size_t)M_ * N1_ * 2;    // h1 f16
  ushort* w2t = (ushort*)p;  p += (size_t)N2_ * N1_ * 2;   // W2^T f16
  unsigned int* q = (unsigned int*)p;                      // 64 counters

  mean_prep_kernel<<<NMB + 288 + 48, 192, 0, stream>>>(
      hidden, seg_ids, mh, W1, w1t, W2, w2t, q);
  fused_gemm<<<NG1 + NG2, 512, 0, stream>>>(
      mh, w1t, b1, h1, w2t, b2, W3, b3, out, q);
}

// Round 13
// 50.871 us; speedup vs baseline: 1.3826x; 1.3826x over previous
//
#include <hip/hip_runtime.h>
#include <hip/hip_fp16.h>

#define B_  64
#define L_  512
#define D_  768
#define S_  64
#define M_  4096
#define N1_ 384
#define N2_ 128
#define SEG_C 4
#define NMB (M_ / SEG_C)      // 1024 mean blocks
#define NW1 24                // W1 swizzle blocks (16 cols each)
#define NW2 8                 // W2 swizzle blocks

typedef __attribute__((ext_vector_type(8))) _Float16 half8;
typedef __attribute__((ext_vector_type(8))) short short8v;
typedef __attribute__((ext_vector_type(4))) float f32x4;

__device__ __forceinline__ ushort f2h(float x) {
  return __half_as_ushort(__float2half_rn(x));
}

// ---------------------------------------------------------------------------
// Kernel 1: blocks 0..1023 streaming segment-mean (R9 form, measured 18us =
// BW floor). Blocks 1024..1055: weight swizzle — write W1^T / W2^T in MFMA
// B-fragment lane order: blob(ntile,kt)[lane][8] = W[kt*32+(lane>>4)*8+e]
// [ntile*16+(lane&15)], so the MLP kernel can load fragments as coalesced
// 16B/lane global reads with no LDS staging and no k-loop barriers.
// ---------------------------------------------------------------------------
__global__ __launch_bounds__(192) void mean_prep_kernel(
    const float* __restrict__ hidden, const int* __restrict__ seg_ids,
    ushort* __restrict__ means,
    const float* __restrict__ W1, ushort* __restrict__ w1s,
    const float* __restrict__ W2, ushort* __restrict__ w2s) {
  const int bid = blockIdx.x;
  const int tid = threadIdx.x;

  if (bid < NMB) {
    const int b  = bid >> 4;
    const int s0 = (bid & 15) * SEG_C;
    __shared__ int sids[L_];
    __shared__ int wred[3];
    int pk = 0;
    if (tid < 128) {
      int4 v = ((const int4*)(seg_ids + b * L_))[tid];
      ((int4*)sids)[tid] = v;
      int clo = (v.x < s0) + (v.y < s0) + (v.z < s0) + (v.w < s0);
      int chi = (v.x < s0 + SEG_C) + (v.y < s0 + SEG_C) +
                (v.z < s0 + SEG_C) + (v.w < s0 + SEG_C);
      pk = clo * 1024 + chi;
    }
    #pragma unroll
    for (int off = 1; off < 64; off <<= 1) pk += __shfl_xor(pk, off);
    if ((tid & 63) == 0) wred[tid >> 6] = pk;
    __syncthreads();
    const int tot = wred[0] + wred[1] + wred[2];
    const int lo = tot >> 10;
    const int hi = tot & 1023;

    const float4* hp = (const float4*)(hidden + (size_t)b * L_ * D_) + tid;
    ushort* outb = means + (size_t)b * S_ * D_ + tid * 4;
    const uint2 zz = {0u, 0u};

    int cur = (lo < hi) ? sids[lo] : s0 + SEG_C;
    for (int z = s0; z < cur; ++z)
      *(uint2*)(outb + (size_t)z * D_) = zz;

    float4 acc = {0.0f, 0.0f, 0.0f, 0.0f};
    int segstart = lo;
    for (int l = lo; l < hi; l += 8) {
      float4 v[8];
      int sv[8];
      #pragma unroll
      for (int k = 0; k < 8; ++k) {
        v[k]  = hp[(size_t)min(l + k, hi - 1) * (D_ / 4)];
        sv[k] = sids[min(l + k + 1, hi - 1)];
      }
      #pragma unroll
      for (int k = 0; k < 8; ++k) {
        if (l + k < hi) {
          acc.x += v[k].x; acc.y += v[k].y;
          acc.z += v[k].z; acc.w += v[k].w;
          const int nx = l + k + 1;
          if (nx == hi || sv[k] != cur) {
            const float inv = 1.0f / (float)(nx - segstart);
            ushort4 h;
            h.x = f2h(acc.x * inv); h.y = f2h(acc.y * inv);
            h.z = f2h(acc.z * inv); h.w = f2h(acc.w * inv);
            *(ushort4*)(outb + (size_t)cur * D_) = h;
            const int nxt = (nx == hi) ? s0 + SEG_C : sv[k];
            for (int z = cur + 1; z < nxt; ++z)
              *(uint2*)(outb + (size_t)z * D_) = zz;
            acc.x = 0.0f; acc.y = 0.0f; acc.z = 0.0f; acc.w = 0.0f;
            segstart = nx; cur = nxt;
          }
        }
      }
    }
  } else if (bid < NMB + NW1) {
    // ---- W1 swizzle: one 16-col ntile, 24 k-tiles of 32 -> 1536 blobs ----
    const int wb = bid - NMB;
    const int n0 = wb * 16;
    #pragma unroll 1
    for (int i = 0; i < 8; ++i) {
      const int slot = i * 192 + tid;          // 0..1535
      const int kt = slot >> 6, l = slot & 63;
      short8v r;
      #pragma unroll
      for (int e = 0; e < 8; ++e) {
        float x = W1[(size_t)(kt * 32 + ((l >> 4) << 3) + e) * N1_ + n0 + (l & 15)];
        r[e] = (short)f2h(x);
      }
      *(short8v*)(w1s + ((size_t)wb * 1536 + slot) * 8) = r;
    }
  } else {
    // ---- W2 swizzle: one 16-col ntile, 12 k-tiles -> 768 blobs ----
    const int wb = bid - NMB - NW1;
    const int n0 = wb * 16;
    #pragma unroll 1
    for (int i = 0; i < 4; ++i) {
      const int slot = i * 192 + tid;          // 0..767
      const int kt = slot >> 6, l = slot & 63;
      short8v r;
      #pragma unroll
      for (int e = 0; e < 8; ++e) {
        float x = W2[(size_t)(kt * 32 + ((l >> 4) << 3) + e) * N2_ + n0 + (l & 15)];
        r[e] = (short)f2h(x);
      }
      *(short8v*)(w2s + ((size_t)wb * 768 + slot) * 8) = r;
    }
  }
}

// ---------------------------------------------------------------------------
// Kernel 2: fully-fused per-sample MLP. 64 blocks x 512 thr (8 waves).
//  stage: means[sample] 64x768 f16 -> LDS [64][776] (2-way banks)
//  phase1: h1 = relu(means @ W1 + b1); wave w owns cols [48w,48w+48);
//          A-frags ds_read_b128 from LDS, B-frags coalesced 16B/lane from
//          swizzled w1s (L2-hot) -> NO barriers in k-loop.
//  h1 (64x392 f16) written into LDS over the dead means region.
//  phase2: h2 = relu(h1 @ W2 + b2) in regs; epilogue x W3 shfl-reduce -> out.
// ---------------------------------------------------------------------------
__global__ __launch_bounds__(512, 1) void mlp_fused(
    const ushort* __restrict__ means, const ushort* __restrict__ w1s,
    const float* __restrict__ b1, const ushort* __restrict__ w2s,
    const float* __restrict__ b2, const float* __restrict__ W3,
    const float* __restrict__ b3, float* __restrict__ out) {
  __shared__ __align__(16) char lds[99840];
  ushort* sM = (ushort*)lds;               // [64][776]
  ushort* sH = (ushort*)lds;               // [64][392], reuses means region
  float*  pl = (float*)(lds + 99328);      // 128 floats
  const int tid  = threadIdx.x;
  const int wid  = tid >> 6;
  const int lane = tid & 63;
  const int lrow = lane & 15;
  const int lk   = (lane >> 4) * 8;
  const int b    = blockIdx.x;

  // ---- stage means (coalesced 16B chunks) ----
  {
    const int row = tid >> 3, j = tid & 7;
    const ushort* src = means + (size_t)(b * 64 + row) * D_;
    ushort* dst = sM + row * 776;
    #pragma unroll
    for (int i = 0; i < 12; ++i) {
      const int k = (j * 12 + i) * 8;
      *(uint4*)(dst + k) = *(const uint4*)(src + k);
    }
  }
  __syncthreads();

  // ---- phase 1: 24 k-tiles, no barriers ----
  f32x4 acc[4][3] = {};
  {
    const ushort* bp0 = w1s + ((size_t)(3 * wid) * 24) * 512 + lane * 8;
    #pragma unroll 1
    for (int kt = 0; kt < 24; ++kt) {
      half8 bf[3];
      #pragma unroll
      for (int j = 0; j < 3; ++j)
        bf[j] = *(const half8*)(bp0 + ((size_t)j * 24 + kt) * 512);
      half8 af[4];
      #pragma unroll
      for (int mi = 0; mi < 4; ++mi)
        af[mi] = *(const half8*)&sM[(mi * 16 + lrow) * 776 + kt * 32 + lk];
      #pragma unroll
      for (int mi = 0; mi < 4; ++mi)
        #pragma unroll
        for (int j = 0; j < 3; ++j)
          acc[mi][j] = __builtin_amdgcn_mfma_f32_16x16x32_f16(af[mi], bf[j], acc[mi][j], 0, 0, 0);
    }
  }
  __syncthreads();   // all means reads done; region becomes h1

  // ---- h1 -> LDS (bias + relu), f16 [64][392] ----
  #pragma unroll
  for (int mi = 0; mi < 4; ++mi)
    #pragma unroll
    for (int j = 0; j < 3; ++j) {
      const int n = (3 * wid + j) * 16 + lrow;
      const float bj = b1[n];
      #pragma unroll
      for (int r = 0; r < 4; ++r) {
        const int m = mi * 16 + (lane >> 4) * 4 + r;
        sH[m * 392 + n] = f2h(fmaxf(acc[mi][j][r] + bj, 0.0f));
      }
    }
  __syncthreads();

  // ---- phase 2: rows half x 32-col group per wave ----
  f32x4 a2[2][2] = {};
  const int m0 = (wid >> 2) * 32;
  const int c2 = wid & 3;
  {
    const ushort* bp = w2s + ((size_t)(c2 * 2) * 12) * 512 + lane * 8;
    #pragma unroll 1
    for (int kt = 0; kt < 12; ++kt) {
      half8 bf[2];
      bf[0] = *(const half8*)(bp + (size_t)kt * 512);
      bf[1] = *(const half8*)(bp + (size_t)(12 + kt) * 512);
      half8 af[2];
      #pragma unroll
      for (int i = 0; i < 2; ++i)
        af[i] = *(const half8*)&sH[(m0 + i * 16 + lrow) * 392 + kt * 32 + lk];
      #pragma unroll
      for (int i = 0; i < 2; ++i)
        #pragma unroll
        for (int j = 0; j < 2; ++j)
          a2[i][j] = __builtin_amdgcn_mfma_f32_16x16x32_f16(af[i], bf[j], a2[i][j], 0, 0, 0);
    }
  }

  // ---- epilogue: h2 = relu(a2 + b2); logits = h2 @ W3 + b3 ----
  if (tid < 128) pl[tid] = 0.0f;
  float w3v[2][2], b2v[2];
  #pragma unroll
  for (int j = 0; j < 2; ++j) {
    const int col = c2 * 32 + j * 16 + lrow;
    w3v[j][0] = W3[col * 2 + 0];
    w3v[j][1] = W3[col * 2 + 1];
    b2v[j] = b2[col];
  }
  __syncthreads();
  #pragma unroll
  for (int i = 0; i < 2; ++i)
    #pragma unroll
    for (int r = 0; r < 4; ++r) {
      float p0 = 0.0f, p1 = 0.0f;
      #pragma unroll
      for (int j = 0; j < 2; ++j) {
        float v = fmaxf(a2[i][j][r] + b2v[j], 0.0f);
        p0 += v * w3v[j][0];
        p1 += v * w3v[j][1];
      }
      p0 += __shfl_xor(p0, 1); p1 += __shfl_xor(p1, 1);
      p0 += __shfl_xor(p0, 2); p1 += __shfl_xor(p1, 2);
      p0 += __shfl_xor(p0, 4); p1 += __shfl_xor(p1, 4);
      p0 += __shfl_xor(p0, 8); p1 += __shfl_xor(p1, 8);
      if (lrow == 0) {
        const int row = m0 + i * 16 + (lane >> 4) * 4 + r;   // 0..63
        atomicAdd(&pl[row * 2 + 0], p0);
        atomicAdd(&pl[row * 2 + 1], p1);
      }
    }
  __syncthreads();
  if (tid < 128) {
    const int row = tid >> 1, c = tid & 1;
    out[(size_t)(b * 64 + row) * 2 + c] = pl[tid] + b3[c];
  }
}

// ---------------------------------------------------------------------------
extern "C" void kernel_launch(void* const* d_in, const int* in_sizes, int n_in,
                              void* d_out, int out_size, void* d_ws, size_t ws_size,
                              hipStream_t stream) {
  const float* hidden  = (const float*)d_in[0];
  const int*   seg_ids = (const int*)d_in[1];
  const float* W1 = (const float*)d_in[2];
  const float* b1 = (const float*)d_in[3];
  const float* W2 = (const float*)d_in[4];
  const float* b2 = (const float*)d_in[5];
  const float* W3 = (const float*)d_in[6];
  const float* b3 = (const float*)d_in[7];
  float* out = (float*)d_out;

  char* p = (char*)d_ws;
  ushort* means = (ushort*)p;  p += (size_t)M_ * D_ * 2;      // 6.29 MB
  ushort* w1s   = (ushort*)p;  p += (size_t)N1_ * D_ * 2;     // 0.59 MB swz
  ushort* w2s   = (ushort*)p;  p += (size_t)N2_ * N1_ * 2;    // 98 KB swz

  mean_prep_kernel<<<NMB + NW1 + NW2, 192, 0, stream>>>(
      hidden, seg_ids, means, W1, w1s, W2, w2s);
  mlp_fused<<<B_, 512, 0, stream>>>(
      means, w1s, b1, w2s, b2, W3, b3, out);
}

// Round 14
// 36.067 us; speedup vs baseline: 1.9501x; 1.4104x over previous
//
#include <hip/hip_runtime.h>
#include <hip/hip_fp16.h>

#define B_  64
#define L_  512
#define D_  768
#define S_  64
#define M_  4096
#define N1_ 384
#define N2_ 128
#define SEG_C 4
#define NMB (M_ / SEG_C)      // 1024 mean blocks
#define NW1 24                // W1 swizzle blocks (16 cols each)
#define NW2 8                 // W2 swizzle blocks

typedef __attribute__((ext_vector_type(8))) _Float16 half8;
typedef __attribute__((ext_vector_type(8))) short short8v;
typedef __attribute__((ext_vector_type(4))) float f32x4;

__device__ __forceinline__ ushort f2h(float x) {
  return __half_as_ushort(__float2half_rn(x));
}

// ---------------------------------------------------------------------------
// Kernel 1 (R9-proven mean + R13-proven weight swizzle):
//  blocks 0..1023: streaming segment-mean -> means f16, natural [M][D].
//  blocks 1024..1055: weight swizzle to MFMA B-fragment lane order:
//  blob(ntile,kt)[lane][e] = W[kt*32+(lane>>4)*8+e][ntile*16+(lane&15)].
// ---------------------------------------------------------------------------
__global__ __launch_bounds__(192) void mean_prep_kernel(
    const float* __restrict__ hidden, const int* __restrict__ seg_ids,
    ushort* __restrict__ means,
    const float* __restrict__ W1, ushort* __restrict__ w1s,
    const float* __restrict__ W2, ushort* __restrict__ w2s) {
  const int bid = blockIdx.x;
  const int tid = threadIdx.x;

  if (bid < NMB) {
    const int b  = bid >> 4;
    const int s0 = (bid & 15) * SEG_C;
    __shared__ int sids[L_];
    __shared__ int wred[3];
    int pk = 0;
    if (tid < 128) {
      int4 v = ((const int4*)(seg_ids + b * L_))[tid];
      ((int4*)sids)[tid] = v;
      int clo = (v.x < s0) + (v.y < s0) + (v.z < s0) + (v.w < s0);
      int chi = (v.x < s0 + SEG_C) + (v.y < s0 + SEG_C) +
                (v.z < s0 + SEG_C) + (v.w < s0 + SEG_C);
      pk = clo * 1024 + chi;
    }
    #pragma unroll
    for (int off = 1; off < 64; off <<= 1) pk += __shfl_xor(pk, off);
    if ((tid & 63) == 0) wred[tid >> 6] = pk;
    __syncthreads();
    const int tot = wred[0] + wred[1] + wred[2];
    const int lo = tot >> 10;
    const int hi = tot & 1023;

    const float4* hp = (const float4*)(hidden + (size_t)b * L_ * D_) + tid;
    ushort* outb = means + (size_t)b * S_ * D_ + tid * 4;
    const uint2 zz = {0u, 0u};

    int cur = (lo < hi) ? sids[lo] : s0 + SEG_C;
    for (int z = s0; z < cur; ++z)
      *(uint2*)(outb + (size_t)z * D_) = zz;

    float4 acc = {0.0f, 0.0f, 0.0f, 0.0f};
    int segstart = lo;
    for (int l = lo; l < hi; l += 8) {
      float4 v[8];
      int sv[8];
      #pragma unroll
      for (int k = 0; k < 8; ++k) {
        v[k]  = hp[(size_t)min(l + k, hi - 1) * (D_ / 4)];
        sv[k] = sids[min(l + k + 1, hi - 1)];
      }
      #pragma unroll
      for (int k = 0; k < 8; ++k) {
        if (l + k < hi) {
          acc.x += v[k].x; acc.y += v[k].y;
          acc.z += v[k].z; acc.w += v[k].w;
          const int nx = l + k + 1;
          if (nx == hi || sv[k] != cur) {
            const float inv = 1.0f / (float)(nx - segstart);
            ushort4 h;
            h.x = f2h(acc.x * inv); h.y = f2h(acc.y * inv);
            h.z = f2h(acc.z * inv); h.w = f2h(acc.w * inv);
            *(ushort4*)(outb + (size_t)cur * D_) = h;
            const int nxt = (nx == hi) ? s0 + SEG_C : sv[k];
            for (int z = cur + 1; z < nxt; ++z)
              *(uint2*)(outb + (size_t)z * D_) = zz;
            acc.x = 0.0f; acc.y = 0.0f; acc.z = 0.0f; acc.w = 0.0f;
            segstart = nx; cur = nxt;
          }
        }
      }
    }
  } else if (bid < NMB + NW1) {
    // ---- W1 swizzle: one 16-col ntile, 24 k-tiles of 32 -> 1536 blobs ----
    const int wb = bid - NMB;
    const int n0 = wb * 16;
    #pragma unroll 1
    for (int i = 0; i < 8; ++i) {
      const int slot = i * 192 + tid;          // 0..1535
      const int kt = slot >> 6, l = slot & 63;
      short8v r;
      #pragma unroll
      for (int e = 0; e < 8; ++e) {
        float x = W1[(size_t)(kt * 32 + ((l >> 4) << 3) + e) * N1_ + n0 + (l & 15)];
        r[e] = (short)f2h(x);
      }
      *(short8v*)(w1s + ((size_t)wb * 1536 + slot) * 8) = r;
    }
  } else {
    // ---- W2 swizzle: one 16-col ntile, 12 k-tiles -> 768 blobs ----
    const int wb = bid - NMB - NW1;
    const int n0 = wb * 16;
    #pragma unroll 1
    for (int i = 0; i < 4; ++i) {
      const int slot = i * 192 + tid;          // 0..767
      const int kt = slot >> 6, l = slot & 63;
      short8v r;
      #pragma unroll
      for (int e = 0; e < 8; ++e) {
        float x = W2[(size_t)(kt * 32 + ((l >> 4) << 3) + e) * N2_ + n0 + (l & 15)];
        r[e] = (short)f2h(x);
      }
      *(short8v*)(w2s + ((size_t)wb * 768 + slot) * 8) = r;
    }
  }
}

// ---------------------------------------------------------------------------
// Kernel 2: fused MLP per QUARTER-sample (16 rows). Grid 256 = 64 samples x 4
// quarters -> 1 block/CU, all CUs busy (fixes R13's 64-block underfill).
//  stage: means rows [b*64+qs*16, +16) x 768 -> LDS [16][776] (coalesced)
//  phase1: h1 = relu(A @ W1 + b1); wave w owns 3 col-tiles (48 cols);
//          A-frags ds_read from LDS; B-frags coalesced 16B/lane from
//          swizzled w1s (L2-resident 576 KB) -> zero k-loop barriers.
//  h1 (16x384 f16) -> LDS; phase2: wave w owns 1 col-tile of W2;
//  epilogue: x W3 shfl + LDS-atomic reduce -> out (32 values).
// ---------------------------------------------------------------------------
__global__ __launch_bounds__(512, 1) void mlp_q(
    const ushort* __restrict__ means, const ushort* __restrict__ w1s,
    const float* __restrict__ b1, const ushort* __restrict__ w2s,
    const float* __restrict__ b2, const float* __restrict__ W3,
    const float* __restrict__ b3, float* __restrict__ out) {
  __shared__ __align__(16) char lds[37504];
  ushort* sM = (ushort*)lds;                 // [16][776] = 24832 B
  ushort* sH = (ushort*)(lds + 24832);       // [16][392] = 12544 B
  float*  pl = (float*)(lds + 37376);        // 32 floats
  const int tid  = threadIdx.x;
  const int wid  = tid >> 6;
  const int lane = tid & 63;
  const int lrow = lane & 15;
  const int lk   = (lane >> 4) * 8;
  const int b    = blockIdx.x >> 2;
  const int qs   = blockIdx.x & 3;
  const int row0 = b * 64 + qs * 16;

  // ---- stage 16x768 means (coalesced: 1536 uint4, 3 per thread) ----
  {
    const ushort* src = means + (size_t)row0 * D_;
    #pragma unroll
    for (int i = 0; i < 3; ++i) {
      const int g = tid + 512 * i;           // 0..1535
      const int r = g / 96, c8 = g % 96;     // 96 uint4 per row
      *(uint4*)(sM + r * 776 + c8 * 8) = *(const uint4*)(src + r * 768 + c8 * 8);
    }
  }
  if (tid < 32) pl[tid] = 0.0f;
  __syncthreads();

  // ---- phase 1: 24 k-tiles, no barriers; wave owns ntiles 3w..3w+2 ----
  f32x4 acc[3] = {};
  {
    const ushort* bp = w1s + (size_t)(3 * wid) * 24 * 512 + lane * 8;
    #pragma unroll 4
    for (int kt = 0; kt < 24; ++kt) {
      half8 af = *(const half8*)&sM[lrow * 776 + kt * 32 + lk];
      half8 bf[3];
      #pragma unroll
      for (int j = 0; j < 3; ++j)
        bf[j] = *(const half8*)(bp + ((size_t)j * 24 + kt) * 512);
      #pragma unroll
      for (int j = 0; j < 3; ++j)
        acc[j] = __builtin_amdgcn_mfma_f32_16x16x32_f16(af, bf[j], acc[j], 0, 0, 0);
    }
  }
  // h1 -> LDS (bias + relu): row=(lane>>4)*4+r, col=(3wid+j)*16+lrow
  #pragma unroll
  for (int j = 0; j < 3; ++j) {
    const int n = (3 * wid + j) * 16 + lrow;
    const float bj = b1[n];
    #pragma unroll
    for (int r = 0; r < 4; ++r) {
      const int m = (lane >> 4) * 4 + r;
      sH[m * 392 + n] = f2h(fmaxf(acc[j][r] + bj, 0.0f));
    }
  }
  __syncthreads();

  // ---- phase 2: 12 k-tiles; wave owns W2 ntile = wid (16 cols) ----
  f32x4 a2 = {};
  {
    const ushort* bp = w2s + (size_t)wid * 12 * 512 + lane * 8;
    #pragma unroll 4
    for (int kt = 0; kt < 12; ++kt) {
      half8 af = *(const half8*)&sH[lrow * 392 + kt * 32 + lk];
      half8 bf = *(const half8*)(bp + (size_t)kt * 512);
      a2 = __builtin_amdgcn_mfma_f32_16x16x32_f16(af, bf, a2, 0, 0, 0);
    }
  }

  // ---- epilogue: h2 = relu(a2 + b2); logits = h2 @ W3 + b3 ----
  const int col = wid * 16 + lrow;
  const float w30 = W3[col * 2 + 0];
  const float w31 = W3[col * 2 + 1];
  const float b2v = b2[col];
  #pragma unroll
  for (int r = 0; r < 4; ++r) {
    float v = fmaxf(a2[r] + b2v, 0.0f);
    float p0 = v * w30;
    float p1 = v * w31;
    p0 += __shfl_xor(p0, 1); p1 += __shfl_xor(p1, 1);
    p0 += __shfl_xor(p0, 2); p1 += __shfl_xor(p1, 2);
    p0 += __shfl_xor(p0, 4); p1 += __shfl_xor(p1, 4);
    p0 += __shfl_xor(p0, 8); p1 += __shfl_xor(p1, 8);
    if (lrow == 0) {
      const int row = (lane >> 4) * 4 + r;   // 0..15
      atomicAdd(&pl[row * 2 + 0], p0);
      atomicAdd(&pl[row * 2 + 1], p1);
    }
  }
  __syncthreads();
  if (tid < 32) {
    const int row = tid >> 1, c = tid & 1;
    out[(size_t)(row0 + row) * 2 + c] = pl[tid] + b3[c];
  }
}

// ---------------------------------------------------------------------------
extern "C" void kernel_launch(void* const* d_in, const int* in_sizes, int n_in,
                              void* d_out, int out_size, void* d_ws, size_t ws_size,
                              hipStream_t stream) {
  const float* hidden  = (const float*)d_in[0];
  const int*   seg_ids = (const int*)d_in[1];
  const float* W1 = (const float*)d_in[2];
  const float* b1 = (const float*)d_in[3];
  const float* W2 = (const float*)d_in[4];
  const float* b2 = (const float*)d_in[5];
  const float* W3 = (const float*)d_in[6];
  const float* b3 = (const float*)d_in[7];
  float* out = (float*)d_out;

  char* p = (char*)d_ws;
  ushort* means = (ushort*)p;  p += (size_t)M_ * D_ * 2;      // 6.29 MB
  ushort* w1s   = (ushort*)p;  p += (size_t)N1_ * D_ * 2;     // 0.59 MB swz
  ushort* w2s   = (ushort*)p;  p += (size_t)N2_ * N1_ * 2;    // 98 KB swz

  mean_prep_kernel<<<NMB + NW1 + NW2, 192, 0, stream>>>(
      hidden, seg_ids, means, W1, w1s, W2, w2s);
  mlp_q<<<B_ * 4, 512, 0, stream>>>(
      means, w1s, b1, w2s, b2, W3, b3, out);
}